// Round 5
// baseline (371.519 us; speedup 1.0000x reference)
//
#include <hip/hip_runtime.h>

#define B_ 64
#define C_ 256
#define TV_ 1600
#define V_ 25
#define H_ 8

typedef __attribute__((ext_vector_type(2))) int   intx2;
typedef __attribute__((ext_vector_type(4))) int   intx4;
typedef __attribute__((ext_vector_type(2))) float floatx2;
typedef __attribute__((ext_vector_type(4))) float floatx4;
typedef __attribute__((ext_vector_type(8))) short short8;

__device__ __forceinline__ unsigned short f2bf(float f) {
    union { float f; unsigned u; } c; c.f = f;
    unsigned u = c.u;
    u += 0x7fffu + ((u >> 16) & 1u);   // RNE (no NaN inputs in this problem)
    return (unsigned short)(u >> 16);
}
__device__ __forceinline__ float bf2f(unsigned short s) {
    union { unsigned u; float f; } c; c.u = ((unsigned)s) << 16;
    return c.f;
}
__device__ __forceinline__ int pk_bf2(float a, float b) {
    return (int)((unsigned)f2bf(a) | ((unsigned)f2bf(b) << 16));
}

// ---------------- Kz: zero OA+L (blocks 0..527); cast vw/pw -> bf16 (blocks 528..591) ----
__global__ __launch_bounds__(256) void kz_zero(float* __restrict__ zbase,
        const float* __restrict__ vw, const float* __restrict__ pw,
        unsigned short* __restrict__ VWB, unsigned short* __restrict__ PWB) {
    const int blk = blockIdx.x;
    if (blk < 528) {
        const int i = blk * 256 + threadIdx.x;   // 528*256 = 135168 float4 = 2,162,688 B
        ((floatx4*)zbase)[i] = (floatx4){0.f, 0.f, 0.f, 0.f};
    } else {
        const int g = (blk - 528) * 256 + threadIdx.x;  // 16384 float4
        const floatx4 v = ((const floatx4*)vw)[g];
        const floatx4 p = ((const floatx4*)pw)[g];
        ((intx2*)VWB)[g] = (intx2){pk_bf2(v[0], v[1]), pk_bf2(v[2], v[3])};
        ((intx2*)PWB)[g] = (intx2){pk_bf2(p[0], p[1]), pk_bf2(p[2], p[3])};
    }
}

// ---------------- K0: Qt[b,h,25,256] bf16 = temp[h]/sqrt(32)*log2e * (xc @ qw_h^T) @ kw_h ----
__global__ __launch_bounds__(256) void k0_qtilde(const float* __restrict__ xcls,
        const float* __restrict__ qw, const float* __restrict__ kw,
        const float* __restrict__ temp, unsigned short* __restrict__ QT) {
    __shared__ float xq[25 * 260];    // [q][c]
    __shared__ float qh[25 * 33];     // [q][d]
    __shared__ float kws[32 * 264];   // [d][c]
    const int blk = blockIdx.x;
    const int b = blk >> 3, h = blk & 7;
    const int t = threadIdx.x;
    {
        const float* src = xcls + ((size_t)(b * C_ + t)) * V_;
        #pragma unroll
        for (int q = 0; q < V_; q++) xq[q * 260 + t] = src[q];
    }
    {
        const int d = t >> 3, c0 = (t & 7) * 32;
        const float* src = kw + (size_t)(h * 32 + d) * C_ + c0;
        #pragma unroll
        for (int j4 = 0; j4 < 8; j4++)
            *(floatx4*)&kws[d * 264 + c0 + 4 * j4] = *(const floatx4*)(src + 4 * j4);
    }
    __syncthreads();
    for (int idx = t; idx < 800; idx += 256) {
        const int q = idx >> 5, d = idx & 31;
        const float* qwr = qw + (size_t)(h * 32 + d) * C_;
        float acc = 0.f;
        for (int c4 = 0; c4 < 64; c4++) {
            const floatx4 a = *(const floatx4*)(qwr + 4 * c4);
            const floatx4 x = *(const floatx4*)&xq[q * 260 + 4 * c4];
            acc += a[0] * x[0] + a[1] * x[1] + a[2] * x[2] + a[3] * x[3];
        }
        qh[q * 33 + d] = acc;
    }
    __syncthreads();
    const float scale = temp[h] * 0.17677669529663689f * 1.4426950408889634f;
    const int qp = t & 31, cg = t >> 5;
    const int c0 = cg * 32;
    if (qp < 25) {
        floatx4 a4[8];
        #pragma unroll
        for (int j = 0; j < 8; j++) a4[j] = (floatx4){0.f, 0.f, 0.f, 0.f};
        for (int d = 0; d < 32; d++) {
            const float a = qh[qp * 33 + d];
            #pragma unroll
            for (int j4 = 0; j4 < 8; j4++) {
                const floatx4 k4 = *(const floatx4*)&kws[d * 264 + c0 + 4 * j4];
                a4[j4][0] += a * k4[0]; a4[j4][1] += a * k4[1];
                a4[j4][2] += a * k4[2]; a4[j4][3] += a * k4[3];
            }
        }
        unsigned short* dst = QT + ((size_t)((b * H_ + h) * 25 + qp)) * C_ + c0;
        #pragma unroll
        for (int j8 = 0; j8 < 4; j8++) {
            intx4 w;
            w[0] = pk_bf2(scale * a4[j8 * 2][0],     scale * a4[j8 * 2][1]);
            w[1] = pk_bf2(scale * a4[j8 * 2][2],     scale * a4[j8 * 2][3]);
            w[2] = pk_bf2(scale * a4[j8 * 2 + 1][0], scale * a4[j8 * 2 + 1][1]);
            w[3] = pk_bf2(scale * a4[j8 * 2 + 1][2], scale * a4[j8 * 2 + 1][3]);
            *(intx4*)(dst + j8 * 8) = w;
        }
    }
}

// ---------------- K2: block=(b, s of 160 n-rows), 8 waves = 8 heads ----
// x_patch read fp32 directly (k1 fused): thread (cg=tid>>4, l16=tid&15) owns chunks
// 2*tid,2*tid+1 = (cg, n=2*l16, 2*l16+1); 8 float2 loads (128B-coalesced per 16 lanes),
// packed to bf16 in regs, ds_write 2x16B. Same RNE as old k1 -> identical numerics.
__global__ __launch_bounds__(512, 4) void k2_attn(
        const float* __restrict__ xp, const unsigned short* __restrict__ QT,
        const unsigned short* __restrict__ VWB, float* __restrict__ OA,
        float* __restrict__ L) {
    __shared__ unsigned short Xs[8192];        // 1024 chunks x 16B, frag-major
    __shared__ unsigned short Ps[8][32 * 40];  // per-head P  [q][n], pad 40
    __shared__ unsigned short Vs[8][32 * 40];  // per-head V^T [d][n], pad 40

    const int blk = blockIdx.x;
    const int b = blk & 63, s = blk >> 6;      // s-twins of b share XCD (64%8==0)
    const int tid = threadIdx.x;
    const int h = tid >> 6;                    // wave == head
    const int lane = tid & 63;
    const int quad = lane >> 4, l16 = lane & 15;
    const int cg = tid >> 4;                   // 0..31 (c-group of 8)

    short8 qf[2][8];
    {
        const unsigned short* qb = QT + (size_t)(b * H_ + h) * 25 * C_;
        #pragma unroll
        for (int mt = 0; mt < 2; mt++)
            #pragma unroll
            for (int ks = 0; ks < 8; ks++)
                qf[mt][ks] = *(const short8*)(qb + (mt * 16 + l16) * C_ + ks * 32 + quad * 8);
    }
    short8 vwf[2][8];
    #pragma unroll
    for (int dt = 0; dt < 2; dt++)
        #pragma unroll
        for (int ks = 0; ks < 8; ks++)
            vwf[dt][ks] = *(const short8*)(VWB + (size_t)(h * 32 + dt * 16 + l16) * C_ + ks * 32 + quad * 8);

    floatx4 oc[2][2];
    #pragma unroll
    for (int mt = 0; mt < 2; mt++)
        #pragma unroll
        for (int dt = 0; dt < 2; dt++) oc[mt][dt] = (floatx4){0.f, 0.f, 0.f, 0.f};
    float lsum[2][4];
    #pragma unroll
    for (int mt = 0; mt < 2; mt++)
        #pragma unroll
        for (int r = 0; r < 4; r++) lsum[mt][r] = 0.f;

    const float* xp_b = xp + (size_t)b * C_ * TV_ + s * 160 + 2 * l16;
    floatx2 pf[8];
    #pragma unroll
    for (int k = 0; k < 8; k++)
        pf[k] = *(const floatx2*)(xp_b + (size_t)(cg * 8 + k) * TV_);

    for (int ti = 0; ti < 5; ti++) {
        {   // pack + store this tile
            intx4 w0, w1;
            w0[0] = pk_bf2(pf[0][0], pf[1][0]); w0[1] = pk_bf2(pf[2][0], pf[3][0]);
            w0[2] = pk_bf2(pf[4][0], pf[5][0]); w0[3] = pk_bf2(pf[6][0], pf[7][0]);
            w1[0] = pk_bf2(pf[0][1], pf[1][1]); w1[1] = pk_bf2(pf[2][1], pf[3][1]);
            w1[2] = pk_bf2(pf[4][1], pf[5][1]); w1[3] = pk_bf2(pf[6][1], pf[7][1]);
            *(intx4*)&Xs[(tid * 2 + 0) * 8] = w0;
            *(intx4*)&Xs[(tid * 2 + 1) * 8] = w1;
        }
        __syncthreads();
        if (ti < 4) {   // prefetch next tile's fp32
            const float* nxt = xp_b + (ti + 1) * 32;
            #pragma unroll
            for (int k = 0; k < 8; k++)
                pf[k] = *(const floatx2*)(nxt + (size_t)(cg * 8 + k) * TV_);
        }
        floatx4 sc[2][2], va[2][2];
        #pragma unroll
        for (int i = 0; i < 2; i++)
            #pragma unroll
            for (int j = 0; j < 2; j++) {
                sc[i][j] = (floatx4){0.f, 0.f, 0.f, 0.f};
                va[i][j] = (floatx4){0.f, 0.f, 0.f, 0.f};
            }
        #pragma unroll
        for (int ks = 0; ks < 8; ks++) {
            const short8 xf0 = *(const short8*)&Xs[(((ks * 4 + quad) * 32) + l16) * 8];
            const short8 xf1 = *(const short8*)&Xs[(((ks * 4 + quad) * 32) + 16 + l16) * 8];
            sc[0][0] = __builtin_amdgcn_mfma_f32_16x16x32_bf16(qf[0][ks], xf0, sc[0][0], 0, 0, 0);
            sc[0][1] = __builtin_amdgcn_mfma_f32_16x16x32_bf16(qf[0][ks], xf1, sc[0][1], 0, 0, 0);
            sc[1][0] = __builtin_amdgcn_mfma_f32_16x16x32_bf16(qf[1][ks], xf0, sc[1][0], 0, 0, 0);
            sc[1][1] = __builtin_amdgcn_mfma_f32_16x16x32_bf16(qf[1][ks], xf1, sc[1][1], 0, 0, 0);
            va[0][0] = __builtin_amdgcn_mfma_f32_16x16x32_bf16(xf0, vwf[0][ks], va[0][0], 0, 0, 0);
            va[0][1] = __builtin_amdgcn_mfma_f32_16x16x32_bf16(xf0, vwf[1][ks], va[0][1], 0, 0, 0);
            va[1][0] = __builtin_amdgcn_mfma_f32_16x16x32_bf16(xf1, vwf[0][ks], va[1][0], 0, 0, 0);
            va[1][1] = __builtin_amdgcn_mfma_f32_16x16x32_bf16(xf1, vwf[1][ks], va[1][1], 0, 0, 0);
        }
        #pragma unroll
        for (int mt = 0; mt < 2; mt++)
            #pragma unroll
            for (int g = 0; g < 2; g++)
                #pragma unroll
                for (int r = 0; r < 4; r++) {
                    const float p = __builtin_amdgcn_exp2f(sc[mt][g][r]);
                    lsum[mt][r] += p;
                    Ps[h][(mt * 16 + quad * 4 + r) * 40 + g * 16 + l16] = f2bf(p);
                }
        #pragma unroll
        for (int g = 0; g < 2; g++)
            #pragma unroll
            for (int dt = 0; dt < 2; dt++)
                *(intx2*)&Vs[h][(dt * 16 + l16) * 40 + g * 16 + quad * 4] =
                    (intx2){pk_bf2(va[g][dt][0], va[g][dt][1]),
                            pk_bf2(va[g][dt][2], va[g][dt][3])};
        #pragma unroll
        for (int mt = 0; mt < 2; mt++) {
            const short8 pa = *(const short8*)&Ps[h][(mt * 16 + l16) * 40 + quad * 8];
            #pragma unroll
            for (int dt = 0; dt < 2; dt++) {
                const short8 vb = *(const short8*)&Vs[h][(dt * 16 + l16) * 40 + quad * 8];
                oc[mt][dt] = __builtin_amdgcn_mfma_f32_16x16x32_bf16(pa, vb, oc[mt][dt], 0, 0, 0);
            }
        }
        __syncthreads();   // all waves done with Xs before next ds_write
    }
    #pragma unroll
    for (int mt = 0; mt < 2; mt++)
        #pragma unroll
        for (int r = 0; r < 4; r++) {
            float v = lsum[mt][r];
            #pragma unroll
            for (int off = 1; off < 16; off <<= 1) v += __shfl_xor(v, off, 64);
            lsum[mt][r] = v;
        }
    const size_t bh = (size_t)(b * H_ + h);
    if (l16 == 0) {
        #pragma unroll
        for (int mt = 0; mt < 2; mt++)
            #pragma unroll
            for (int r = 0; r < 4; r++) {
                const int q = mt * 16 + quad * 4 + r;
                if (q < 25) atomicAdd(&L[bh * 32 + q], lsum[mt][r]);
            }
    }
    #pragma unroll
    for (int mt = 0; mt < 2; mt++)
        #pragma unroll
        for (int dt = 0; dt < 2; dt++)
            #pragma unroll
            for (int r = 0; r < 4; r++) {
                const int q = mt * 16 + quad * 4 + r;
                if (q < 25)
                    atomicAdd(&OA[bh * 1024 + q * 32 + dt * 16 + l16], oc[mt][dt][r]);
            }
}

// ---------------- K3 (MFMA): y[b,i,q] = pb[i] + sum_j pw[i,j] * OAnorm[b,q,j] ----------
__global__ __launch_bounds__(256) void k3_proj(const float* __restrict__ OA,
        const float* __restrict__ Lsum, const unsigned short* __restrict__ PWB,
        const float* __restrict__ pb, float* __restrict__ y) {
    __shared__ unsigned short OB[32 * 264];   // normalized O bf16, rows 25..31 zero
    __shared__ float rl_s[256];
    const int blk = blockIdx.x;
    const int b = blk >> 1, i0 = (blk & 1) * 128;
    const int t = threadIdx.x;
    const int wv = t >> 6, lane = t & 63;
    const int quad = lane >> 4, l16 = lane & 15;
    {
        const int h = t >> 5, q = t & 31;
        const float lv = Lsum[(size_t)(b * H_ + h) * 32 + q];
        rl_s[t] = (q < 25) ? 1.0f / lv : 0.0f;
    }
    __syncthreads();
    for (int idx = t; idx < 8192; idx += 256) {
        const int q = idx >> 8, j = idx & 255;
        const int h2 = j >> 5, d = j & 31;
        const float val = (q < 25)
            ? OA[(size_t)(b * H_ + h2) * 1024 + q * 32 + d] * rl_s[h2 * 32 + q] : 0.f;
        OB[q * 264 + j] = f2bf(val);
    }
    __syncthreads();
    floatx4 oc[2][2];
    #pragma unroll
    for (int mt = 0; mt < 2; mt++)
        #pragma unroll
        for (int ntp = 0; ntp < 2; ntp++) oc[mt][ntp] = (floatx4){0.f, 0.f, 0.f, 0.f};
    #pragma unroll
    for (int ks = 0; ks < 8; ks++) {
        const short8 a0 = *(const short8*)&OB[l16 * 264 + ks * 32 + quad * 8];
        const short8 a1 = *(const short8*)&OB[(16 + l16) * 264 + ks * 32 + quad * 8];
        #pragma unroll
        for (int ntp = 0; ntp < 2; ntp++) {
            const int i = i0 + (wv * 2 + ntp) * 16 + l16;
            const short8 bv = *(const short8*)(PWB + (size_t)i * C_ + ks * 32 + quad * 8);
            oc[0][ntp] = __builtin_amdgcn_mfma_f32_16x16x32_bf16(a0, bv, oc[0][ntp], 0, 0, 0);
            oc[1][ntp] = __builtin_amdgcn_mfma_f32_16x16x32_bf16(a1, bv, oc[1][ntp], 0, 0, 0);
        }
    }
    #pragma unroll
    for (int ntp = 0; ntp < 2; ntp++) {
        const int i = i0 + (wv * 2 + ntp) * 16 + l16;
        const float bias = pb[i];
        #pragma unroll
        for (int mt = 0; mt < 2; mt++)
            #pragma unroll
            for (int r = 0; r < 4; r++) {
                const int q = mt * 16 + quad * 4 + r;
                if (q < 25) y[(size_t)b * 6400 + i * 25 + q] = oc[mt][ntp][r] + bias;
            }
    }
}

extern "C" void kernel_launch(void* const* d_in, const int* in_sizes, int n_in,
                              void* d_out, int out_size, void* d_ws, size_t ws_size,
                              hipStream_t stream) {
    const float* xcls = (const float*)d_in[0];
    const float* xp   = (const float*)d_in[1];
    const float* qw   = (const float*)d_in[2];
    const float* kw   = (const float*)d_in[3];
    const float* vw   = (const float*)d_in[4];
    const float* temp = (const float*)d_in[5];
    const float* pw   = (const float*)d_in[6];
    const float* pb   = (const float*)d_in[7];
    float* y = (float*)d_out;

    // ws: QT 6,553,600(+8,192 pad) | OA 2,097,152 | L 65,536 | VWB 131,072 | PWB 131,072
    if (ws_size < (size_t)8986624) return;
    char* ws = (char*)d_ws;
    unsigned short* QT  = (unsigned short*)ws;
    float*          OA  = (float*)(ws + 6561792);
    float*          L   = (float*)(ws + 8658944);
    unsigned short* VWB = (unsigned short*)(ws + 8724480);
    unsigned short* PWB = (unsigned short*)(ws + 8855552);

    hipLaunchKernelGGL(kz_zero,  dim3(592), dim3(256), 0, stream, OA, vw, pw, VWB, PWB);
    hipLaunchKernelGGL(k0_qtilde,dim3(512), dim3(256), 0, stream, xcls, qw, kw, temp, QT);
    hipLaunchKernelGGL(k2_attn,  dim3(640), dim3(512), 0, stream, xp, QT, VWB, OA, L);
    hipLaunchKernelGGL(k3_proj,  dim3(128), dim3(256), 0, stream, OA, L, PWB, pb, y);
}